// Round 4
// baseline (19274.434 us; speedup 1.0000x reference)
//
#include <hip/hip_runtime.h>

// ---------------------------------------------------------------------------
// Teacher_model_7464653160858: embed+BN -> 3x GRU(1024, reset_after) -> dense+softmax
// B=64, T=512, E=256, U=1024, V=512.
//
// R4: wave-specialized gru_seq.
//  w0/w1: compute. kc-split (16 k-chunks each), all 4 row-tiles, all 3 gates.
//         B-frag LDS traffic halved vs R3 (96KB/step). Symmetric 2-way
//         K-reduce (12KB, conflict-free layout). Gating split w0=rows 0..31,
//         w1=rows 32..63.
//  w2:    poller. ONE lane polls ONE per-step counter line (R3 flooded MALL
//         with 4096 same-line atomic loads/round -> serialization).
//  w3:    xp prefetcher. Double-buffered xp -> LDS (f32), removing 12
//         scattered global loads from the critical waves.
//  Publish: per-wave s_waitcnt vmcnt(0) + LDS token -> one atomicAdd per WG
//  on a dedicated 64B-strided counter. Cross-dispatch coherence via AQL
//  kernel acquire/release fences (standard HIP semantics).
// ---------------------------------------------------------------------------

typedef short bf16x8 __attribute__((ext_vector_type(8)));
typedef float f32x4 __attribute__((ext_vector_type(4)));
typedef unsigned short ushort_t;

#define MFMA16(a, b, c) __builtin_amdgcn_mfma_f32_16x16x32_bf16((a), (b), (c), 0, 0, 0)

#define TC 128            // T-chunk
#define SLAB 65536        // elems per h slab: 128 u8-groups * 64 b * 8

__device__ __forceinline__ float bf2f(ushort_t h) {
    return __uint_as_float(((unsigned)h) << 16);
}
__device__ __forceinline__ ushort_t f2bf(float f) {
    unsigned u = __float_as_uint(f);
    u += 0x7FFFu + ((u >> 16) & 1u);   // RNE
    return (ushort_t)(u >> 16);
}
__device__ __forceinline__ float sigmf(float x) { return 1.f / (1.f + __expf(-x)); }
__device__ __forceinline__ float tanhfast(float x) {
    float e = __expf(2.f * x);
    return 1.f - 2.f / (e + 1.f);
}

// ---------------------------------------------------------------------------
// pack: W[K][3072] fp32 -> WT[3072][K] bf16 (transpose). grid (K/64, 48).
// ---------------------------------------------------------------------------
__global__ __launch_bounds__(256, 1) void pack_w(
    const float* __restrict__ W, ushort_t* __restrict__ WT, int K)
{
    __shared__ ushort_t tile[64][72];
    const int kt0 = blockIdx.x * 64;
    const int ct0 = blockIdx.y * 64;
    const int tx = threadIdx.x & 63;
    const int ty = threadIdx.x >> 6;
#pragma unroll
    for (int i = 0; i < 16; ++i) {
        int k = kt0 + ty * 16 + i;
        tile[ty * 16 + i][tx] = f2bf(W[(size_t)k * 3072 + ct0 + tx]);
    }
    __syncthreads();
#pragma unroll
    for (int i = 0; i < 16; ++i) {
        int c = ct0 + ty * 16 + i;
        WT[(size_t)c * K + kt0 + tx] = tile[tx][ty * 16 + i];
    }
}

// ---------------------------------------------------------------------------
// BN-folded embedding table (512x256 bf16)
// ---------------------------------------------------------------------------
__global__ __launch_bounds__(256, 1) void embed_bn(
    const float* __restrict__ emb,
    const float* __restrict__ gamma, const float* __restrict__ beta,
    const float* __restrict__ mean, const float* __restrict__ var,
    ushort_t* __restrict__ embBN)
{
    const int idx = blockIdx.x * 256 + threadIdx.x;
    const int e = idx & 255;
    const float sc = gamma[e] * rsqrtf(var[e] + 1e-3f);
    const float sh = beta[e] - mean[e] * sc;
    embBN[idx] = f2bf(fmaf(emb[idx], sc, sh));
}

// ---------------------------------------------------------------------------
// xp_gemm (verified): xp[b*TC+s][3072] = A @ WkT^T. 128x128 tile, BK=32.
// ---------------------------------------------------------------------------
__global__ __launch_bounds__(256, 2) void xp_gemm(
    const ushort_t* __restrict__ Asrc, const int* __restrict__ tokens,
    const ushort_t* __restrict__ WkT, ushort_t* __restrict__ xp,
    int K, int t0)
{
    const int tid = threadIdx.x;
    const int b = blockIdx.x;
    const int cb = blockIdx.y * 128;
    const int lane = tid & 63, w = tid >> 6;
    const int n = lane & 15, quad = lane >> 4;
    __shared__ ushort_t sA[128 * 40], sB[128 * 40];

    const int m0 = tid >> 2, kq0 = (tid & 3) * 8;
    const int m1 = m0 + 64;
    const ushort_t *ga0, *ga1;
    if (tokens) {
        ga0 = Asrc + (size_t)tokens[b * 512 + t0 + m0] * 256;
        ga1 = Asrc + (size_t)tokens[b * 512 + t0 + m1] * 256;
    } else {
        ga0 = Asrc + ((size_t)b * 512 + t0 + m0) * 1024;
        ga1 = Asrc + ((size_t)b * 512 + t0 + m1) * 1024;
    }
    const ushort_t* gb0 = WkT + (size_t)(cb + m0) * K;
    const ushort_t* gb1 = WkT + (size_t)(cb + m1) * K;

    f32x4 acc[4][4] = {};
    const int rw = (w & 1) * 64, cw = (w >> 1) * 64;

    for (int kb = 0; kb < K; kb += 32) {
        __syncthreads();
        *(bf16x8*)(sA + m0 * 40 + kq0) = *(const bf16x8*)(ga0 + kb + kq0);
        *(bf16x8*)(sA + m1 * 40 + kq0) = *(const bf16x8*)(ga1 + kb + kq0);
        *(bf16x8*)(sB + m0 * 40 + kq0) = *(const bf16x8*)(gb0 + kb + kq0);
        *(bf16x8*)(sB + m1 * 40 + kq0) = *(const bf16x8*)(gb1 + kb + kq0);
        __syncthreads();
        bf16x8 Af[4], Bf[4];
#pragma unroll
        for (int rt = 0; rt < 4; ++rt)
            Af[rt] = *(const bf16x8*)(sA + (rw + rt * 16 + n) * 40 + quad * 8);
#pragma unroll
        for (int nt = 0; nt < 4; ++nt)
            Bf[nt] = *(const bf16x8*)(sB + (cw + nt * 16 + n) * 40 + quad * 8);
#pragma unroll
        for (int rt = 0; rt < 4; ++rt)
#pragma unroll
            for (int nt = 0; nt < 4; ++nt)
                acc[rt][nt] = MFMA16(Af[rt], Bf[nt], acc[rt][nt]);
    }
#pragma unroll
    for (int rt = 0; rt < 4; ++rt)
#pragma unroll
        for (int nt = 0; nt < 4; ++nt)
#pragma unroll
            for (int reg = 0; reg < 4; ++reg) {
                float v = acc[rt][nt][reg];
                float v2 = __shfl_xor(v, 1);
                if ((lane & 1) == 0) {
                    int row = rw + rt * 16 + quad * 4 + reg;
                    int col = cb + cw + nt * 16 + n;
                    unsigned pk = (unsigned)f2bf(v) | ((unsigned)f2bf(v2) << 16);
                    *(unsigned*)(xp + ((size_t)b * TC + row) * 3072 + col) = pk;
                }
            }
}

// ---------------------------------------------------------------------------
// gru_seq v4: wave-specialized. 64 WGs x 256 thr. WG wg owns u [wg*16,+16).
// ---------------------------------------------------------------------------
__global__ __launch_bounds__(256, 1) void gru_seq(
    const ushort_t* __restrict__ xp,    // [64*TC][3072]
    const ushort_t* __restrict__ WrT,   // [3072][1024]
    const float* __restrict__ gb,       // [2][3072] flat
    ushort_t* __restrict__ seq,         // [64][512][1024]
    ushort_t* __restrict__ Hx,          // [TC][SLAB] bf16
    float* __restrict__ Hf,             // [64][1024] fp32 carry
    unsigned* __restrict__ cnt,         // [1536*16] dwords, zeroed per launch
    int sBase, int t0, int first, int writeSeq)
{
    __shared__ ushort_t ldsW[48 * 1032];          // 99,072 B Wr slice
    __shared__ float red[2][2][3][64][4];         // 12,288 B [src][rtl][g][lane][reg]
    __shared__ float xvS[2][3][16][68];           // 26,112 B [parity][g][u][b(+pad)]
    __shared__ int ldsTok;

    const int tid = threadIdx.x;
    const int wg = blockIdx.x;
    const int lane = tid & 63;
    const int w = tid >> 6;
    const int n = lane & 15, quad = lane >> 4;
    const int u_ = wg * 16 + n;

    // ---- stage Wr slice (all threads) ----
    for (int idx = tid; idx < 48 * 128; idx += 256) {
        int r = idx >> 7, ko = (idx & 127) * 8;
        int g = r >> 4, nn = r & 15;
        *(bf16x8*)(ldsW + r * 1032 + ko) =
            *(const bf16x8*)(WrT + ((size_t)(g * 1024 + wg * 16 + nn)) * 1024 + ko);
    }
    if (tid == 0) ldsTok = 0;

    const float bzz = gb[u_] + gb[3072 + u_];
    const float brr = gb[1024 + u_] + gb[3072 + 1024 + u_];
    const float bxh = gb[2048 + u_];
    const float brh = gb[3072 + 2048 + u_];

    // compute-wave h carry (w0: rows 0..31, w1: rows 32..63)
    float hcur[8];
    if (w < 2) {
#pragma unroll
        for (int j = 0; j < 8; ++j) {
            int b = (w * 2 + (j >> 2)) * 16 + quad * 4 + (j & 3);
            hcur[j] = first ? 0.f : Hf[b * 1024 + u_];
        }
    }

    // w3 preamble: xvS[0] for s=0, then hold regs for s=1
    bf16x8 xq[6];
    if (w == 3) {
        const ushort_t* xr = xp + ((size_t)lane * TC + t0 - t0 + 0) * 3072 + wg * 16;
        // note: row index is lane*TC + s with s local to this chunk
#pragma unroll
        for (int g = 0; g < 3; ++g) {
            xq[g * 2 + 0] = *(const bf16x8*)(xr + g * 1024);
            xq[g * 2 + 1] = *(const bf16x8*)(xr + g * 1024 + 8);
        }
#pragma unroll
        for (int g = 0; g < 3; ++g)
#pragma unroll
            for (int h = 0; h < 2; ++h)
#pragma unroll
                for (int j = 0; j < 8; ++j)
                    xvS[0][g][h * 8 + j][lane] = bf2f(((ushort_t*)&xq[g * 2 + h])[j]);
        if (TC > 1) {
            const ushort_t* x1 = xp + ((size_t)lane * TC + 1) * 3072 + wg * 16;
#pragma unroll
            for (int g = 0; g < 3; ++g) {
                xq[g * 2 + 0] = *(const bf16x8*)(x1 + g * 1024);
                xq[g * 2 + 1] = *(const bf16x8*)(x1 + g * 1024 + 8);
            }
        }
    }
    __syncthreads();

    f32x4 acc[4][3];

    for (int s = 0; s < TC; ++s) {
        const int gs = sBase + s;

        // ================= phase 0: wait for h_{gs-1} =================
        if (w == 2 && lane == 0 && gs > 0) {
            while (__hip_atomic_load(&cnt[(size_t)(gs - 1) * 16], __ATOMIC_RELAXED,
                                     __HIP_MEMORY_SCOPE_AGENT) < 64u)
                __builtin_amdgcn_s_sleep(1);
        }
        __syncthreads();

        // ================= phase 1: MFMA (w0/w1) | xp prefetch (w3) ====
        if (w < 2) {
#pragma unroll
            for (int rt = 0; rt < 4; ++rt)
#pragma unroll
                for (int g = 0; g < 3; ++g)
                    acc[rt][g] = (f32x4){0.f, 0.f, 0.f, 0.f};
            if (gs > 0) {
                const ushort_t* slab = Hx + (size_t)((s + TC - 1) & (TC - 1)) * SLAB;
#pragma unroll
                for (int kc = 0; kc < 16; ++kc) {
                    const int kcg = w * 16 + kc;
                    const ushort_t* hb = slab + (size_t)(kcg * 4 + quad) * 512;
                    bf16x8 A0 = *(const bf16x8*)(hb + (0 * 16 + n) * 8);
                    bf16x8 A1 = *(const bf16x8*)(hb + (1 * 16 + n) * 8);
                    bf16x8 A2 = *(const bf16x8*)(hb + (2 * 16 + n) * 8);
                    bf16x8 A3 = *(const bf16x8*)(hb + (3 * 16 + n) * 8);
#pragma unroll
                    for (int g = 0; g < 3; ++g) {
                        bf16x8 B = *(const bf16x8*)(ldsW + (size_t)(g * 16 + n) * 1032 +
                                                    kcg * 32 + quad * 8);
                        acc[0][g] = MFMA16(A0, B, acc[0][g]);
                        acc[1][g] = MFMA16(A1, B, acc[1][g]);
                        acc[2][g] = MFMA16(A2, B, acc[2][g]);
                        acc[3][g] = MFMA16(A3, B, acc[3][g]);
                    }
                }
            }
            // write partner partials (rows the OTHER wave gates)
            const int other = 1 - w;
#pragma unroll
            for (int rtl = 0; rtl < 2; ++rtl)
#pragma unroll
                for (int g = 0; g < 3; ++g)
                    *(f32x4*)&red[w][rtl][g][lane][0] = acc[2 * other + rtl][g];
        } else if (w == 3) {
            if (s + 1 < TC) {
#pragma unroll
                for (int g = 0; g < 3; ++g)
#pragma unroll
                    for (int h = 0; h < 2; ++h)
#pragma unroll
                        for (int j = 0; j < 8; ++j)
                            xvS[(s + 1) & 1][g][h * 8 + j][lane] =
                                bf2f(((ushort_t*)&xq[g * 2 + h])[j]);
                if (s + 2 < TC) {
                    const ushort_t* x2 = xp + ((size_t)lane * TC + s + 2) * 3072 + wg * 16;
#pragma unroll
                    for (int g = 0; g < 3; ++g) {
                        xq[g * 2 + 0] = *(const bf16x8*)(x2 + g * 1024);
                        xq[g * 2 + 1] = *(const bf16x8*)(x2 + g * 1024 + 8);
                    }
                }
            }
        }
        __syncthreads();

        // ================= phase 2: reduce + gating + publish (w0/w1) ==
        if (w < 2) {
            ushort_t* hxW = (ushort_t*)Hx + (size_t)(s & (TC - 1)) * SLAB;
            const int p = s & 1;
#pragma unroll
            for (int rtl = 0; rtl < 2; ++rtl) {
                const int rt = 2 * w + rtl;
                f32x4 tZ = acc[rt][0] + *(const f32x4*)&red[1 - w][rtl][0][lane][0];
                f32x4 tR = acc[rt][1] + *(const f32x4*)&red[1 - w][rtl][1][lane][0];
                f32x4 tH = acc[rt][2] + *(const f32x4*)&red[1 - w][rtl][2][lane][0];
                f32x4 xz = *(const f32x4*)&xvS[p][0][n][rt * 16 + quad * 4];
                f32x4 xr = *(const f32x4*)&xvS[p][1][n][rt * 16 + quad * 4];
                f32x4 xh = *(const f32x4*)&xvS[p][2][n][rt * 16 + quad * 4];
#pragma unroll
                for (int i = 0; i < 4; ++i) {
                    float z = sigmf(tZ[i] + xz[i] + bzz);
                    float r = sigmf(tR[i] + xr[i] + brr);
                    float hh = tanhfast(xh[i] + bxh + r * (tH[i] + brh));
                    float hn = z * hcur[rtl * 4 + i] + (1.f - z) * hh;
                    hcur[rtl * 4 + i] = hn;
                    float hn2 = __shfl_xor(hn, 1);
                    if ((lane & 1) == 0) {
                        unsigned pk = (unsigned)f2bf(hn) | ((unsigned)f2bf(hn2) << 16);
                        int b = rt * 16 + quad * 4 + i;
                        size_t e = ((size_t)(u_ >> 3) * 64 + b) * 8 + (u_ & 7);
                        __hip_atomic_store((unsigned*)hxW + (e >> 1), pk,
                                           __ATOMIC_RELAXED, __HIP_MEMORY_SCOPE_AGENT);
                        if (writeSeq)
                            *(unsigned*)(seq + ((size_t)b * 512 + t0 + s) * 1024 + u_) = pk;
                    }
                }
            }
            // drain own stores, then token handshake, then single add
            asm volatile("s_waitcnt vmcnt(0)" ::: "memory");
            if (w == 1 && lane == 0) {
                __atomic_store_n(&ldsTok, s + 1, __ATOMIC_RELEASE);
            }
            if (w == 0 && lane == 0) {
                while (__atomic_load_n(&ldsTok, __ATOMIC_ACQUIRE) < s + 1) {}
                __hip_atomic_fetch_add(&cnt[(size_t)gs * 16], 1u,
                                       __ATOMIC_RELAXED, __HIP_MEMORY_SCOPE_AGENT);
            }
        }
    }

    // final h carry (write-through so next dispatch sees it regardless of XCD)
    if (w < 2) {
#pragma unroll
        for (int j = 0; j < 8; ++j) {
            int b = (w * 2 + (j >> 2)) * 16 + quad * 4 + (j & 3);
            __hip_atomic_store(&Hf[b * 1024 + u_], hcur[j],
                               __ATOMIC_RELAXED, __HIP_MEMORY_SCOPE_AGENT);
        }
    }
}

// ---------------------------------------------------------------------------
// dense + softmax (verified). One WG per (b,f).
// ---------------------------------------------------------------------------
__global__ __launch_bounds__(256, 1) void dense_softmax(
    const float* __restrict__ hfinal, const float* __restrict__ Wd,
    const float* __restrict__ bd, float* __restrict__ out)
{
    const int tid = threadIdx.x;
    const int bf = blockIdx.x;
    __shared__ float sv[256];
    __shared__ float red[256];
    sv[tid] = hfinal[bf * 256 + tid];
    __syncthreads();
    float a0 = bd[tid], a1 = bd[tid + 256];
    for (int d = 0; d < 256; ++d) {
        float s = sv[d];
        a0 = fmaf(s, Wd[d * 512 + tid], a0);
        a1 = fmaf(s, Wd[d * 512 + tid + 256], a1);
    }
    red[tid] = fmaxf(a0, a1);
    __syncthreads();
    for (int st = 128; st > 0; st >>= 1) {
        if (tid < st) red[tid] = fmaxf(red[tid], red[tid + st]);
        __syncthreads();
    }
    const float mx = red[0];
    __syncthreads();
    float e0 = __expf(a0 - mx), e1 = __expf(a1 - mx);
    red[tid] = e0 + e1;
    __syncthreads();
    for (int st = 128; st > 0; st >>= 1) {
        if (tid < st) red[tid] += red[tid + st];
        __syncthreads();
    }
    const float inv = 1.f / red[0];
    out[(size_t)bf * 512 + tid] = e0 * inv;
    out[(size_t)bf * 512 + tid + 256] = e1 * inv;
}

// ---------------------------------------------------------------------------
extern "C" void kernel_launch(void* const* d_in, const int* in_sizes, int n_in,
                              void* d_out, int out_size, void* d_ws, size_t ws_size,
                              hipStream_t stream)
{
    (void)in_sizes; (void)n_in; (void)out_size; (void)ws_size;

    const int*   tokens = (const int*)d_in[0];
    const float* emb    = (const float*)d_in[1];
    const float* gamma  = (const float*)d_in[2];
    const float* beta   = (const float*)d_in[3];
    const float* mean   = (const float*)d_in[4];
    const float* var    = (const float*)d_in[5];
    const float* gk[3]  = {(const float*)d_in[6], (const float*)d_in[9],  (const float*)d_in[12]};
    const float* gr[3]  = {(const float*)d_in[7], (const float*)d_in[10], (const float*)d_in[13]};
    const float* gbb[3] = {(const float*)d_in[8], (const float*)d_in[11], (const float*)d_in[14]};
    const float* dw  = (const float*)d_in[15];
    const float* db  = (const float*)d_in[16];

    // workspace carve (~161 MB)
    char* p = (char*)d_ws;
    ushort_t* seq   = (ushort_t*)p; p += (size_t)64 * 512 * 1024 * 2;   // 67.1 MB
    ushort_t* xp    = (ushort_t*)p; p += (size_t)64 * TC * 3072 * 2;    // 50.3 MB
    ushort_t* WkT0  = (ushort_t*)p; p += (size_t)3072 * 256 * 2;
    ushort_t* WkT1  = (ushort_t*)p; p += (size_t)3072 * 1024 * 2;
    ushort_t* WkT2  = (ushort_t*)p; p += (size_t)3072 * 1024 * 2;
    ushort_t* WrT[3];
    for (int l = 0; l < 3; ++l) { WrT[l] = (ushort_t*)p; p += (size_t)3072 * 1024 * 2; }
    ushort_t* embBN = (ushort_t*)p; p += (size_t)512 * 256 * 2;
    ushort_t* Hx    = (ushort_t*)p; p += (size_t)TC * SLAB * 2;         // 16.8 MB
    float*    Hf    = (float*)p;    p += (size_t)64 * 1024 * 4;
    unsigned* cnt   = (unsigned*)p; p += (size_t)1536 * 16 * 4;         // 96 KB

    // MUST zero every launch (graph replay re-poisons ws to 0xAA).
    hipMemsetAsync(cnt, 0, (size_t)1536 * 16 * 4, stream);

    pack_w<<<dim3(4, 48),  256, 0, stream>>>(gk[0], WkT0, 256);
    pack_w<<<dim3(16, 48), 256, 0, stream>>>(gk[1], WkT1, 1024);
    pack_w<<<dim3(16, 48), 256, 0, stream>>>(gk[2], WkT2, 1024);
    for (int l = 0; l < 3; ++l)
        pack_w<<<dim3(16, 48), 256, 0, stream>>>(gr[l], WrT[l], 1024);

    embed_bn<<<512, 256, 0, stream>>>(emb, gamma, beta, mean, var, embBN);

    const ushort_t* WkTl[3] = {WkT0, WkT1, WkT2};
    int dIdx = 0;
    for (int L = 0; L < 3; ++L) {
        for (int c = 0; c < 4; ++c) {
            const int t0 = c * TC;
            if (L == 0)
                xp_gemm<<<dim3(64, 24), 256, 0, stream>>>(embBN, tokens, WkTl[0], xp, 256, t0);
            else
                xp_gemm<<<dim3(64, 24), 256, 0, stream>>>(seq, nullptr, WkTl[L], xp, 1024, t0);
            gru_seq<<<64, 256, 0, stream>>>(
                xp, WrT[L], gbb[L], seq, Hx, Hf, cnt,
                dIdx * TC, t0, (dIdx == 0) ? 1 : 0, (L < 2) ? 1 : 0);
            ++dIdx;
        }
    }

    dense_softmax<<<256, 256, 0, stream>>>(Hf, dw, db, (float*)d_out);
}

// Round 5
// 12185.128 us; speedup vs baseline: 1.5818x; 1.5818x over previous
//
#include <hip/hip_runtime.h>

// ---------------------------------------------------------------------------
// Teacher_model_7464653160858: embed+BN -> 3x GRU(1024, reset_after) -> dense+softmax
// B=64, T=512, E=256, U=1024, V=512.
//
// R5 = R3 structure (4 compute waves, per-WG flags) + three fixes:
//  1. h publish: LDS transpose -> 128x global_store_dwordx4 sc0 sc1 per WG/step
//     (R3/R4 did 512 per-DWORD atomic stores -> ~32K serialized MALL ops/step,
//     the measured ~7us/step floor).
//  2. ldsW stored in exact MFMA frag order: B-frag read = base + lane*16B,
//     conflict-free (R3 stride 516 dw = 8-way conflict, 3.5M conflict cycles).
//  3. flags strided 128B (distinct lines for store & poll).
// ---------------------------------------------------------------------------

typedef short bf16x8 __attribute__((ext_vector_type(8)));
typedef float f32x4 __attribute__((ext_vector_type(4)));
typedef int   i32x4 __attribute__((ext_vector_type(4)));
typedef unsigned short ushort_t;

#define MFMA16(a, b, c) __builtin_amdgcn_mfma_f32_16x16x32_bf16((a), (b), (c), 0, 0, 0)

#define TC 128            // T-chunk
#define SLAB 65536        // elems per h slab: 128 u8-groups * 64 b * 8

__device__ __forceinline__ float bf2f(ushort_t h) {
    return __uint_as_float(((unsigned)h) << 16);
}
__device__ __forceinline__ ushort_t f2bf(float f) {
    unsigned u = __float_as_uint(f);
    u += 0x7FFFu + ((u >> 16) & 1u);   // RNE
    return (ushort_t)(u >> 16);
}
__device__ __forceinline__ float sigmf(float x) { return 1.f / (1.f + __expf(-x)); }
__device__ __forceinline__ float tanhfast(float x) {
    float e = __expf(2.f * x);
    return 1.f - 2.f / (e + 1.f);
}
// 16B write-through store (visible at MALL like relaxed device-scope atomic,
// but coalesced 4x wider than __hip_atomic_store<u32>)
__device__ __forceinline__ void store16_wt(void* dst, i32x4 v) {
    asm volatile("global_store_dwordx4 %0, %1, off sc0 sc1"
                 :: "v"(dst), "v"(v) : "memory");
}

// ---------------------------------------------------------------------------
// pack: W[K][3072] fp32 -> WT[3072][K] bf16 (transpose). grid (K/64, 48).
// ---------------------------------------------------------------------------
__global__ __launch_bounds__(256, 1) void pack_w(
    const float* __restrict__ W, ushort_t* __restrict__ WT, int K)
{
    __shared__ ushort_t tile[64][72];
    const int kt0 = blockIdx.x * 64;
    const int ct0 = blockIdx.y * 64;
    const int tx = threadIdx.x & 63;
    const int ty = threadIdx.x >> 6;
#pragma unroll
    for (int i = 0; i < 16; ++i) {
        int k = kt0 + ty * 16 + i;
        tile[ty * 16 + i][tx] = f2bf(W[(size_t)k * 3072 + ct0 + tx]);
    }
    __syncthreads();
#pragma unroll
    for (int i = 0; i < 16; ++i) {
        int c = ct0 + ty * 16 + i;
        WT[(size_t)c * K + kt0 + tx] = tile[tx][ty * 16 + i];
    }
}

// ---------------------------------------------------------------------------
// BN-folded embedding table (512x256 bf16)
// ---------------------------------------------------------------------------
__global__ __launch_bounds__(256, 1) void embed_bn(
    const float* __restrict__ emb,
    const float* __restrict__ gamma, const float* __restrict__ beta,
    const float* __restrict__ mean, const float* __restrict__ var,
    ushort_t* __restrict__ embBN)
{
    const int idx = blockIdx.x * 256 + threadIdx.x;
    const int e = idx & 255;
    const float sc = gamma[e] * rsqrtf(var[e] + 1e-3f);
    const float sh = beta[e] - mean[e] * sc;
    embBN[idx] = f2bf(fmaf(emb[idx], sc, sh));
}

// ---------------------------------------------------------------------------
// xp_gemm (verified): xp[b*TC+s][3072] = A @ WkT^T. 128x128 tile, BK=32.
// ---------------------------------------------------------------------------
__global__ __launch_bounds__(256, 2) void xp_gemm(
    const ushort_t* __restrict__ Asrc, const int* __restrict__ tokens,
    const ushort_t* __restrict__ WkT, ushort_t* __restrict__ xp,
    int K, int t0)
{
    const int tid = threadIdx.x;
    const int b = blockIdx.x;
    const int cb = blockIdx.y * 128;
    const int lane = tid & 63, w = tid >> 6;
    const int n = lane & 15, quad = lane >> 4;
    __shared__ ushort_t sA[128 * 40], sB[128 * 40];

    const int m0 = tid >> 2, kq0 = (tid & 3) * 8;
    const int m1 = m0 + 64;
    const ushort_t *ga0, *ga1;
    if (tokens) {
        ga0 = Asrc + (size_t)tokens[b * 512 + t0 + m0] * 256;
        ga1 = Asrc + (size_t)tokens[b * 512 + t0 + m1] * 256;
    } else {
        ga0 = Asrc + ((size_t)b * 512 + t0 + m0) * 1024;
        ga1 = Asrc + ((size_t)b * 512 + t0 + m1) * 1024;
    }
    const ushort_t* gb0 = WkT + (size_t)(cb + m0) * K;
    const ushort_t* gb1 = WkT + (size_t)(cb + m1) * K;

    f32x4 acc[4][4] = {};
    const int rw = (w & 1) * 64, cw = (w >> 1) * 64;

    for (int kb = 0; kb < K; kb += 32) {
        __syncthreads();
        *(bf16x8*)(sA + m0 * 40 + kq0) = *(const bf16x8*)(ga0 + kb + kq0);
        *(bf16x8*)(sA + m1 * 40 + kq0) = *(const bf16x8*)(ga1 + kb + kq0);
        *(bf16x8*)(sB + m0 * 40 + kq0) = *(const bf16x8*)(gb0 + kb + kq0);
        *(bf16x8*)(sB + m1 * 40 + kq0) = *(const bf16x8*)(gb1 + kb + kq0);
        __syncthreads();
        bf16x8 Af[4], Bf[4];
#pragma unroll
        for (int rt = 0; rt < 4; ++rt)
            Af[rt] = *(const bf16x8*)(sA + (rw + rt * 16 + n) * 40 + quad * 8);
#pragma unroll
        for (int nt = 0; nt < 4; ++nt)
            Bf[nt] = *(const bf16x8*)(sB + (cw + nt * 16 + n) * 40 + quad * 8);
#pragma unroll
        for (int rt = 0; rt < 4; ++rt)
#pragma unroll
            for (int nt = 0; nt < 4; ++nt)
                acc[rt][nt] = MFMA16(Af[rt], Bf[nt], acc[rt][nt]);
    }
#pragma unroll
    for (int rt = 0; rt < 4; ++rt)
#pragma unroll
        for (int nt = 0; nt < 4; ++nt)
#pragma unroll
            for (int reg = 0; reg < 4; ++reg) {
                float v = acc[rt][nt][reg];
                float v2 = __shfl_xor(v, 1);
                if ((lane & 1) == 0) {
                    int row = rw + rt * 16 + quad * 4 + reg;
                    int col = cb + cw + nt * 16 + n;
                    unsigned pk = (unsigned)f2bf(v) | ((unsigned)f2bf(v2) << 16);
                    *(unsigned*)(xp + ((size_t)b * TC + row) * 3072 + col) = pk;
                }
            }
}

// ---------------------------------------------------------------------------
// gru_seq v5. 64 WGs x 256 thr. WG wg owns u [wg*16,+16).
// waves: w = kh*2+rh (kh = K-half, rh = batch-row-half). R3 structure.
// ---------------------------------------------------------------------------
__global__ __launch_bounds__(256, 1) void gru_seq(
    const ushort_t* __restrict__ xp,    // [64*TC][3072]
    const ushort_t* __restrict__ WrT,   // [3072][1024]
    const float* __restrict__ gb,       // [2][3072] flat
    ushort_t* __restrict__ seq,         // [64][512][1024]
    ushort_t* __restrict__ Hx,          // [TC][SLAB] bf16
    float* __restrict__ Hf,             // [64][1024] fp32 carry
    unsigned* __restrict__ flags,       // [64*32] dwords (128B stride), zeroed/launch
    int sBase, int t0, int first, int writeSeq)
{
    __shared__ ushort_t ldsW[48 * 1024];      // 96 KB, frag-order (conflict-free)
    __shared__ f32x4 ldsRed[12 * 64];         // 12 KB K-reduce
    __shared__ unsigned hT[64 * 12];          // 3 KB publish transpose (pitch 12 dw)

    const int tid = threadIdx.x;
    const int wg = blockIdx.x;
    const int lane = tid & 63;
    const int w = tid >> 6;
    const int kh = w >> 1, rh = w & 1;
    const int n = lane & 15, quad = lane >> 4;
    const int u_ = wg * 16 + n;
    const int rt0 = rh * 2;

    // ---- stage Wr slice, swizzled to exact frag order ----
    // frag addr = ((g*32 + kcg)*64 + lane)*8, lane = quad*16 + n
    for (int idx = tid; idx < 48 * 128; idx += 256) {
        int r = idx >> 7, k8 = idx & 127;
        int g = r >> 4, nn = r & 15;
        int kcg = k8 >> 2, qs = k8 & 3;
        *(bf16x8*)(ldsW + ((g * 32 + kcg) * 64 + qs * 16 + nn) * 8) =
            *(const bf16x8*)(WrT + ((size_t)(g * 1024 + wg * 16 + nn)) * 1024 + k8 * 8);
    }

    const float bzz = gb[u_] + gb[3072 + u_];
    const float brr = gb[1024 + u_] + gb[3072 + 1024 + u_];
    const float bxh = gb[2048 + u_];
    const float brh = gb[3072 + 2048 + u_];

    float hcur[8];                            // kh==0 waves only
    if (kh == 0) {
#pragma unroll
        for (int j = 0; j < 8; ++j) {
            int b = (rt0 + (j >> 2)) * 16 + quad * 4 + (j & 3);
            hcur[j] = first ? 0.f : Hf[b * 1024 + u_];
        }
    }
    __syncthreads();                          // ldsW ready

    for (int s = 0; s < TC; ++s) {
        const int gs = sBase + s;

        // 1. xp prefetch (kh0) - consumed at gating, long latency tolerated
        float xv[2][4][3];
        if (kh == 0) {
#pragma unroll
            for (int rtl = 0; rtl < 2; ++rtl)
#pragma unroll
                for (int i = 0; i < 4; ++i) {
                    int b = (rt0 + rtl) * 16 + quad * 4 + i;
                    const ushort_t* xr = xp + ((size_t)b * TC + s) * 3072 + u_;
#pragma unroll
                    for (int g = 0; g < 3; ++g)
                        xv[rtl][i][g] = bf2f(xr[g * 1024]);
                }
        }

        // 2. wave0 polls 64 distinct lines
        if (w == 0 && gs > 0) {
            while (true) {
                unsigned f = __hip_atomic_load(flags + lane * 32, __ATOMIC_RELAXED,
                                               __HIP_MEMORY_SCOPE_AGENT);
                if (__ballot(f >= (unsigned)gs) == ~0ull) break;
                __builtin_amdgcn_s_sleep(1);
            }
        }
        __syncthreads();
        asm volatile("" ::: "memory");

        // 3. h plain b128 loads + MFMA (B-frag reads conflict-free)
        f32x4 acc[2][3] = {};
        if (gs > 0) {
            const ushort_t* slab = Hx + (size_t)((s + TC - 1) & (TC - 1)) * SLAB;
#pragma unroll
            for (int kc = 0; kc < 16; ++kc) {
                const int kcg = kh * 16 + kc;
                const ushort_t* hb = slab + (size_t)(kcg * 4 + quad) * 512;
                bf16x8 a0 = *(const bf16x8*)(hb + (rt0 * 16 + n) * 8);
                bf16x8 a1 = *(const bf16x8*)(hb + ((rt0 + 1) * 16 + n) * 8);
#pragma unroll
                for (int g = 0; g < 3; ++g) {
                    bf16x8 B = *(const bf16x8*)(ldsW + ((g * 32 + kcg) * 64 + lane) * 8);
                    acc[0][g] = MFMA16(a0, B, acc[0][g]);
                    acc[1][g] = MFMA16(a1, B, acc[1][g]);
                }
            }
        }

        // 4. cross-wave K-reduce: kh1 -> LDS -> kh0
        if (kh == 1) {
#pragma unroll
            for (int rtl = 0; rtl < 2; ++rtl)
#pragma unroll
                for (int g = 0; g < 3; ++g)
                    ldsRed[((rh * 2 + rtl) * 3 + g) * 64 + lane] = acc[rtl][g];
        }
        __syncthreads();

        // 5. gating (kh0) -> hT transpose (+ seq plain stores)
        if (kh == 0) {
#pragma unroll
            for (int rtl = 0; rtl < 2; ++rtl) {
#pragma unroll
                for (int g = 0; g < 3; ++g)
                    acc[rtl][g] += ldsRed[((rh * 2 + rtl) * 3 + g) * 64 + lane];
#pragma unroll
                for (int i = 0; i < 4; ++i) {
                    float z = sigmf(acc[rtl][0][i] + xv[rtl][i][0] + bzz);
                    float r = sigmf(acc[rtl][1][i] + xv[rtl][i][1] + brr);
                    float hh = tanhfast(xv[rtl][i][2] + bxh + r * (acc[rtl][2][i] + brh));
                    float hn = z * hcur[rtl * 4 + i] + (1.f - z) * hh;
                    hcur[rtl * 4 + i] = hn;
                    float hn2 = __shfl_xor(hn, 1);
                    if ((lane & 1) == 0) {
                        unsigned pk = (unsigned)f2bf(hn) | ((unsigned)f2bf(hn2) << 16);
                        int b = (rt0 + rtl) * 16 + quad * 4 + i;
                        hT[b * 12 + (n >> 1)] = pk;
                        if (writeSeq)
                            *(unsigned*)(seq + ((size_t)b * 512 + t0 + s) * 1024 + u_) = pk;
                    }
                }
            }
        }
        __syncthreads();                      // hT ready

        // 6. wide publish: 128 threads x 16B write-through stores
        if (tid < 128) {
            const int b = tid >> 1, half = tid & 1;
            i32x4 v = *(const i32x4*)(hT + b * 12 + half * 4);
            void* dst = (void*)((ushort_t*)Hx + (size_t)(s & (TC - 1)) * SLAB +
                                ((size_t)((wg * 2 + half) * 64 + b)) * 8);
            store16_wt(dst, v);
        }
        asm volatile("s_waitcnt vmcnt(0)" ::: "memory");
        __syncthreads();                      // all drained
        if (tid == 0)
            __hip_atomic_store(flags + wg * 32, (unsigned)(gs + 1),
                               __ATOMIC_RELAXED, __HIP_MEMORY_SCOPE_AGENT);
    }

    if (kh == 0) {
#pragma unroll
        for (int j = 0; j < 8; ++j) {
            int b = (rt0 + (j >> 2)) * 16 + quad * 4 + (j & 3);
            Hf[b * 1024 + u_] = hcur[j];      // plain; kernel-end release flushes
        }
    }
}

// ---------------------------------------------------------------------------
// dense + softmax (verified). One WG per (b,f).
// ---------------------------------------------------------------------------
__global__ __launch_bounds__(256, 1) void dense_softmax(
    const float* __restrict__ hfinal, const float* __restrict__ Wd,
    const float* __restrict__ bd, float* __restrict__ out)
{
    const int tid = threadIdx.x;
    const int bf = blockIdx.x;
    __shared__ float sv[256];
    __shared__ float red[256];
    sv[tid] = hfinal[bf * 256 + tid];
    __syncthreads();
    float a0 = bd[tid], a1 = bd[tid + 256];
    for (int d = 0; d < 256; ++d) {
        float s = sv[d];
        a0 = fmaf(s, Wd[d * 512 + tid], a0);
        a1 = fmaf(s, Wd[d * 512 + tid + 256], a1);
    }
    red[tid] = fmaxf(a0, a1);
    __syncthreads();
    for (int st = 128; st > 0; st >>= 1) {
        if (tid < st) red[tid] = fmaxf(red[tid], red[tid + st]);
        __syncthreads();
    }
    const float mx = red[0];
    __syncthreads();
    float e0 = __expf(a0 - mx), e1 = __expf(a1 - mx);
    red[tid] = e0 + e1;
    __syncthreads();
    for (int st = 128; st > 0; st >>= 1) {
        if (tid < st) red[tid] += red[tid + st];
        __syncthreads();
    }
    const float inv = 1.f / red[0];
    out[(size_t)bf * 512 + tid] = e0 * inv;
    out[(size_t)bf * 512 + tid + 256] = e1 * inv;
}

// ---------------------------------------------------------------------------
extern "C" void kernel_launch(void* const* d_in, const int* in_sizes, int n_in,
                              void* d_out, int out_size, void* d_ws, size_t ws_size,
                              hipStream_t stream)
{
    (void)in_sizes; (void)n_in; (void)out_size; (void)ws_size;

    const int*   tokens = (const int*)d_in[0];
    const float* emb    = (const float*)d_in[1];
    const float* gamma  = (const float*)d_in[2];
    const float* beta   = (const float*)d_in[3];
    const float* mean   = (const float*)d_in[4];
    const float* var    = (const float*)d_in[5];
    const float* gk[3]  = {(const float*)d_in[6], (const float*)d_in[9],  (const float*)d_in[12]};
    const float* gr[3]  = {(const float*)d_in[7], (const float*)d_in[10], (const float*)d_in[13]};
    const float* gbb[3] = {(const float*)d_in[8], (const float*)d_in[11], (const float*)d_in[14]};
    const float* dw  = (const float*)d_in[15];
    const float* db  = (const float*)d_in[16];

    // workspace carve (~161 MB)
    char* p = (char*)d_ws;
    ushort_t* seq   = (ushort_t*)p; p += (size_t)64 * 512 * 1024 * 2;   // 67.1 MB
    ushort_t* xp    = (ushort_t*)p; p += (size_t)64 * TC * 3072 * 2;    // 50.3 MB
    ushort_t* WkT0  = (ushort_t*)p; p += (size_t)3072 * 256 * 2;
    ushort_t* WkT1  = (ushort_t*)p; p += (size_t)3072 * 1024 * 2;
    ushort_t* WkT2  = (ushort_t*)p; p += (size_t)3072 * 1024 * 2;
    ushort_t* WrT[3];
    for (int l = 0; l < 3; ++l) { WrT[l] = (ushort_t*)p; p += (size_t)3072 * 1024 * 2; }
    ushort_t* embBN = (ushort_t*)p; p += (size_t)512 * 256 * 2;
    ushort_t* Hx    = (ushort_t*)p; p += (size_t)TC * SLAB * 2;         // 16.8 MB
    float*    Hf    = (float*)p;    p += (size_t)64 * 1024 * 4;
    unsigned* flags = (unsigned*)p; p += (size_t)64 * 32 * 4;           // 8 KB

    // MUST zero every launch (ws re-poisoned to 0xAA before each timed run).
    hipMemsetAsync(flags, 0, (size_t)64 * 32 * 4, stream);

    pack_w<<<dim3(4, 48),  256, 0, stream>>>(gk[0], WkT0, 256);
    pack_w<<<dim3(16, 48), 256, 0, stream>>>(gk[1], WkT1, 1024);
    pack_w<<<dim3(16, 48), 256, 0, stream>>>(gk[2], WkT2, 1024);
    for (int l = 0; l < 3; ++l)
        pack_w<<<dim3(16, 48), 256, 0, stream>>>(gr[l], WrT[l], 1024);

    embed_bn<<<512, 256, 0, stream>>>(emb, gamma, beta, mean, var, embBN);

    const ushort_t* WkTl[3] = {WkT0, WkT1, WkT2};
    int dIdx = 0;
    for (int L = 0; L < 3; ++L) {
        for (int c = 0; c < 4; ++c) {
            const int t0 = c * TC;
            if (L == 0)
                xp_gemm<<<dim3(64, 24), 256, 0, stream>>>(embBN, tokens, WkTl[0], xp, 256, t0);
            else
                xp_gemm<<<dim3(64, 24), 256, 0, stream>>>(seq, nullptr, WkTl[L], xp, 1024, t0);
            gru_seq<<<64, 256, 0, stream>>>(
                xp, WrT[L], gbb[L], seq, Hx, Hf, flags,
                dIdx * TC, t0, (dIdx == 0) ? 1 : 0, (L < 2) ? 1 : 0);
            ++dIdx;
        }
    }

    dense_softmax<<<256, 256, 0, stream>>>(Hf, dw, db, (float*)d_out);
}